// Round 3
// baseline (1678.800 us; speedup 1.0000x reference)
//
#include <hip/hip_runtime.h>
#include <math.h>

#define EPS 1e-3f
#define H 256
#define QDIM 6
#define DQDIM 4
#define NTRI 10
#define EPB 8   // elements per block

__device__ __forceinline__ float softplusf(float x) {
    if (x > 20.f) return x;
    return log1pf(expf(x));   // expf underflows to 0 for very negative x -> 0, correct
}

__global__ __launch_bounds__(256) void lnn_kernel(
    const float* __restrict__ x,
    const float* __restrict__ mW0, const float* __restrict__ mb0,
    const float* __restrict__ mW1, const float* __restrict__ mb1,
    const float* __restrict__ mW2, const float* __restrict__ mb2,
    const float* __restrict__ vW0, const float* __restrict__ vb0,
    const float* __restrict__ vW1, const float* __restrict__ vb1,
    const float* __restrict__ vW2, const float* __restrict__ vb2,
    float* __restrict__ out, int n)
{
    __shared__ float s_qd[EPB][12];          // q[0..5], dq in [6..9]
    __shared__ float s_h1[EPB][H];
    __shared__ float s_h2[EPB][H];
    __shared__ float s_eh2[EPB * 4][H];      // seeds buffer; reused for eh1, gg1
    __shared__ float s_ent[EPB][NTRI];
    __shared__ float s_entbar[EPB][4][NTRI];
    __shared__ float s_L[EPB][4][4];
    __shared__ float s_J[EPB][4][6];
    __shared__ float s_dV[EPB][6];

    const int tid = threadIdx.x;
    const int e0 = blockIdx.x * EPB;

    // ---- load q, dq ----
    if (tid < EPB * 10) {
        int e = tid / 10, c = tid % 10;
        int ge = e0 + e;
        s_qd[e][c] = (ge < n) ? x[ge * 10 + c] : 0.f;
    }
    __syncthreads();

    // ---- mass MLP layer 0: h1 = tanh(q @ W0 + b0) ----
    {
        const int j = tid;
        float w[QDIM];
        #pragma unroll
        for (int i = 0; i < QDIM; i++) w[i] = mW0[i * H + j];
        const float b = mb0[j];
        #pragma unroll
        for (int e = 0; e < EPB; e++) {
            float z = b;
            #pragma unroll
            for (int i = 0; i < QDIM; i++) z += s_qd[e][i] * w[i];
            s_h1[e][j] = tanhf(z);
        }
    }
    __syncthreads();

    // ---- mass MLP layer 1: h2 = tanh(h1 @ W1 + b1) ----
    {
        const int j = tid;
        float acc[EPB];
        #pragma unroll
        for (int e = 0; e < EPB; e++) acc[e] = 0.f;
        for (int k = 0; k < H; k += 4) {
            const float wa = mW1[(k + 0) * H + j];
            const float wb = mW1[(k + 1) * H + j];
            const float wc = mW1[(k + 2) * H + j];
            const float wd = mW1[(k + 3) * H + j];
            #pragma unroll
            for (int e = 0; e < EPB; e++) {
                const float4 h = *reinterpret_cast<const float4*>(&s_h1[e][k]);
                acc[e] += h.x * wa + h.y * wb + h.z * wc + h.w * wd;
            }
        }
        const float b = mb1[j];
        #pragma unroll
        for (int e = 0; e < EPB; e++) s_h2[e][j] = tanhf(acc[e] + b);
    }
    __syncthreads();

    // ---- ent = h2 @ W2 + b2 ----
    if (tid < EPB * NTRI) {
        int e = tid / NTRI, m = tid % NTRI;
        float acc = mb2[m];
        for (int j = 0; j < H; j++) acc += s_h2[e][j] * mW2[j * NTRI + m];
        s_ent[e][m] = acc;
    }
    __syncthreads();

    // ---- per-element: L, a = L^T dq, ent_bar seeds ----
    if (tid < EPB) {
        const int e = tid;
        const int ti[10] = {0,1,1,2,2,2,3,3,3,3};
        const int tj[10] = {0,0,1,0,1,2,0,1,2,3};
        float L[4][4];
        #pragma unroll
        for (int r = 0; r < 4; r++)
            #pragma unroll
            for (int c = 0; c < 4; c++) L[r][c] = 0.f;
        float sig[10];
        #pragma unroll
        for (int m = 0; m < 10; m++) {
            float v = s_ent[e][m];
            if (ti[m] == tj[m]) {
                sig[m] = 1.f / (1.f + expf(-v));
                L[ti[m]][tj[m]] = softplusf(v);
            } else {
                sig[m] = 1.f;
                L[ti[m]][tj[m]] = v;
            }
        }
        #pragma unroll
        for (int r = 0; r < 4; r++)
            #pragma unroll
            for (int c = 0; c < 4; c++) s_L[e][r][c] = L[r][c];
        float dq[4];
        #pragma unroll
        for (int r = 0; r < 4; r++) dq[r] = s_qd[e][6 + r];
        float a[4];
        #pragma unroll
        for (int c = 0; c < 4; c++) {
            float s = 0.f;
            #pragma unroll
            for (int r = 0; r < 4; r++) s += L[r][c] * dq[r];
            a[c] = s;
        }
        // ent_bar[s][m] = (delta(ti,s)*a[tj] + dq[ti]*L[s][tj]) * (diag? sig : 1)
        #pragma unroll
        for (int s = 0; s < 4; s++) {
            #pragma unroll
            for (int m = 0; m < 10; m++) {
                float v = ((ti[m] == s) ? a[tj[m]] : 0.f) + dq[ti[m]] * L[s][tj[m]];
                s_entbar[e][s][m] = v * sig[m];
            }
        }
    }
    __syncthreads();

    // ---- Eh2[e][s][j] = (1-h2^2) * (W2 @ ent_bar) ----
    {
        const int j = tid;
        float w2row[NTRI];
        #pragma unroll
        for (int m = 0; m < NTRI; m++) w2row[m] = mW2[j * NTRI + m];
        #pragma unroll
        for (int e = 0; e < EPB; e++) {
            const float h = s_h2[e][j];
            const float t2 = 1.f - h * h;
            #pragma unroll
            for (int s = 0; s < 4; s++) {
                float acc = 0.f;
                #pragma unroll
                for (int m = 0; m < NTRI; m++) acc += w2row[m] * s_entbar[e][s][m];
                s_eh2[e * 4 + s][j] = acc * t2;
            }
        }
    }
    __syncthreads();

    // ---- Eh1[e][s][k] = (1-h1^2) * sum_j W1[k,j] * Eh2[e][s][j]  (k = tid) ----
    {
        const int k = tid;
        float acc[EPB * 4];
        #pragma unroll
        for (int es = 0; es < EPB * 4; es++) acc[es] = 0.f;
        for (int m = 0; m < H; m += 4) {
            const float4 w = *reinterpret_cast<const float4*>(&mW1[k * H + m]);
            #pragma unroll
            for (int es = 0; es < EPB * 4; es++) {
                const float4 v = *reinterpret_cast<const float4*>(&s_eh2[es][m]);
                acc[es] += w.x * v.x + w.y * v.y + w.z * v.z + w.w * v.w;
            }
        }
        float t1[EPB];
        #pragma unroll
        for (int e = 0; e < EPB; e++) {
            const float h = s_h1[e][k];
            t1[e] = 1.f - h * h;
        }
        __syncthreads();   // all reads of s_eh2 done before overwrite
        #pragma unroll
        for (int es = 0; es < EPB * 4; es++) s_eh2[es][k] = acc[es] * t1[es / 4];
    }
    __syncthreads();

    // ---- J[e][s][i] = sum_k W0[i,k] * Eh1[e][s][k] ----
    if (tid < EPB * 4 * 6) {
        const int i = tid % 6;
        const int es = tid / 6;
        float acc = 0.f;
        for (int k = 0; k < H; k++) acc += mW0[i * H + k] * s_eh2[es][k];
        s_J[es / 4][es % 4][i] = acc;
    }
    __syncthreads();

    // ---- V MLP layer 0: g1 -> s_h1 (overwrite) ----
    {
        const int j = tid;
        float w[QDIM];
        #pragma unroll
        for (int i = 0; i < QDIM; i++) w[i] = vW0[i * H + j];
        const float b = vb0[j];
        #pragma unroll
        for (int e = 0; e < EPB; e++) {
            float z = b;
            #pragma unroll
            for (int i = 0; i < QDIM; i++) z += s_qd[e][i] * w[i];
            s_h1[e][j] = tanhf(z);
        }
    }
    __syncthreads();

    // ---- V MLP layer 1 + seed: gg2 = (1-g2^2)*vW2[j] -> s_h2 ----
    {
        const int j = tid;
        float acc[EPB];
        #pragma unroll
        for (int e = 0; e < EPB; e++) acc[e] = 0.f;
        for (int k = 0; k < H; k += 4) {
            const float wa = vW1[(k + 0) * H + j];
            const float wb = vW1[(k + 1) * H + j];
            const float wc = vW1[(k + 2) * H + j];
            const float wd = vW1[(k + 3) * H + j];
            #pragma unroll
            for (int e = 0; e < EPB; e++) {
                const float4 h = *reinterpret_cast<const float4*>(&s_h1[e][k]);
                acc[e] += h.x * wa + h.y * wb + h.z * wc + h.w * wd;
            }
        }
        const float b = vb1[j];
        const float w2 = vW2[j];
        #pragma unroll
        for (int e = 0; e < EPB; e++) {
            const float g2 = tanhf(acc[e] + b);
            s_h2[e][j] = (1.f - g2 * g2) * w2;
        }
    }
    __syncthreads();

    // ---- gg1[e][k] = (1-g1^2) * sum_j vW1[k,j] * gg2[e][j] -> s_eh2[e][k] ----
    {
        const int k = tid;
        float acc[EPB];
        #pragma unroll
        for (int e = 0; e < EPB; e++) acc[e] = 0.f;
        for (int m = 0; m < H; m += 4) {
            const float4 w = *reinterpret_cast<const float4*>(&vW1[k * H + m]);
            #pragma unroll
            for (int e = 0; e < EPB; e++) {
                const float4 v = *reinterpret_cast<const float4*>(&s_h2[e][m]);
                acc[e] += w.x * v.x + w.y * v.y + w.z * v.z + w.w * v.w;
            }
        }
        float t1[EPB];
        #pragma unroll
        for (int e = 0; e < EPB; e++) {
            const float g = s_h1[e][k];
            t1[e] = 1.f - g * g;
        }
        __syncthreads();
        #pragma unroll
        for (int e = 0; e < EPB; e++) s_eh2[e][k] = acc[e] * t1[e];
    }
    __syncthreads();

    // ---- dV[e][i] = sum_k vW0[i,k] * gg1[e][k] ----
    if (tid < EPB * 6) {
        const int e = tid / 6, i = tid % 6;
        float acc = 0.f;
        for (int k = 0; k < H; k++) acc += vW0[i * H + k] * s_eh2[e][k];
        s_dV[e][i] = acc;
    }
    __syncthreads();

    // ---- finalize per element ----
    if (tid < EPB && (e0 + tid) < n) {
        const int e = tid;
        float q[6], dq[4];
        #pragma unroll
        for (int i = 0; i < 6; i++) q[i] = s_qd[e][i];
        #pragma unroll
        for (int r = 0; r < 4; r++) dq[r] = s_qd[e][6 + r];
        const float x1a = q[2], x1b = q[3], x2a = q[4], x2b = q[5];
        float J[4][6];
        #pragma unroll
        for (int r = 0; r < 4; r++)
            #pragma unroll
            for (int i = 0; i < 6; i++) J[r][i] = s_J[e][r][i];

        // dqMdq (G)
        float G[4][4];
        #pragma unroll
        for (int r = 0; r < 4; r++) {
            G[r][0] = J[r][0];
            G[r][1] = J[r][1];
            G[r][2] = -x2a * J[r][2] + x1a * J[r][4];
            G[r][3] = -x2b * J[r][3] + x1b * J[r][5];
        }
        // gradL wrt q = 0.5 * J^T dq - dV
        float gL[6];
        #pragma unroll
        for (int i = 0; i < 6; i++) {
            float s = 0.f;
            #pragma unroll
            for (int r = 0; r < 4; r++) s += dq[r] * J[r][i];
            gL[i] = 0.5f * s - s_dV[e][i];
        }
        float dLdq[4];
        dLdq[0] = gL[0];
        dLdq[1] = gL[1];
        dLdq[2] = -x2a * gL[2] + x1a * gL[4];
        dLdq[3] = -x2b * gL[3] + x1b * gL[5];
        // rhs = dLdq - G @ dq
        float b[4];
        #pragma unroll
        for (int r = 0; r < 4; r++) {
            float s = 0.f;
            #pragma unroll
            for (int c = 0; c < 4; c++) s += G[r][c] * dq[c];
            b[r] = dLdq[r] - s;
        }
        // M = L L^T + eps I
        float L[4][4];
        #pragma unroll
        for (int r = 0; r < 4; r++)
            #pragma unroll
            for (int c = 0; c < 4; c++) L[r][c] = s_L[e][r][c];
        float M[4][4];
        #pragma unroll
        for (int r = 0; r < 4; r++)
            #pragma unroll
            for (int c = 0; c <= r; c++) {
                float s = 0.f;
                #pragma unroll
                for (int k = 0; k < 4; k++) s += L[r][k] * L[c][k];
                M[r][c] = s;
            }
        #pragma unroll
        for (int r = 0; r < 4; r++) M[r][r] += EPS;
        // Cholesky
        float C00 = sqrtf(M[0][0]);
        float C10 = M[1][0] / C00, C20 = M[2][0] / C00, C30 = M[3][0] / C00;
        float C11 = sqrtf(M[1][1] - C10 * C10);
        float C21 = (M[2][1] - C20 * C10) / C11;
        float C31 = (M[3][1] - C30 * C10) / C11;
        float C22 = sqrtf(M[2][2] - C20 * C20 - C21 * C21);
        float C32 = (M[3][2] - C30 * C20 - C31 * C21) / C22;
        float C33 = sqrtf(M[3][3] - C30 * C30 - C31 * C31 - C32 * C32);
        // forward solve
        float y0 = b[0] / C00;
        float y1 = (b[1] - C10 * y0) / C11;
        float y2 = (b[2] - C20 * y0 - C21 * y1) / C22;
        float y3 = (b[3] - C30 * y0 - C31 * y1 - C32 * y2) / C33;
        // back solve
        float d3 = y3 / C33;
        float d2 = (y2 - C32 * d3) / C22;
        float d1 = (y1 - C21 * d2 - C31 * d3) / C11;
        float d0 = (y0 - C10 * d1 - C20 * d2 - C30 * d3) / C00;

        float* o = &out[(e0 + e) * 10];
        o[0] = dq[0];
        o[1] = dq[1];
        o[2] = -x2a * dq[2];
        o[3] = -x2b * dq[3];
        o[4] = x1a * dq[2];
        o[5] = x1b * dq[3];
        o[6] = d0; o[7] = d1; o[8] = d2; o[9] = d3;
    }
}

extern "C" void kernel_launch(void* const* d_in, const int* in_sizes, int n_in,
                              void* d_out, int out_size, void* d_ws, size_t ws_size,
                              hipStream_t stream) {
    const float* x   = (const float*)d_in[0];
    const float* mW0 = (const float*)d_in[1];
    const float* mb0 = (const float*)d_in[2];
    const float* mW1 = (const float*)d_in[3];
    const float* mb1 = (const float*)d_in[4];
    const float* mW2 = (const float*)d_in[5];
    const float* mb2 = (const float*)d_in[6];
    const float* vW0 = (const float*)d_in[7];
    const float* vb0 = (const float*)d_in[8];
    const float* vW1 = (const float*)d_in[9];
    const float* vb1 = (const float*)d_in[10];
    const float* vW2 = (const float*)d_in[11];
    const float* vb2 = (const float*)d_in[12];
    float* out = (float*)d_out;
    const int n = in_sizes[0] / 10;
    const int blocks = (n + EPB - 1) / EPB;
    lnn_kernel<<<blocks, 256, 0, stream>>>(x, mW0, mb0, mW1, mb1, mW2, mb2,
                                           vW0, vb0, vW1, vb1, vW2, vb2, out, n);
}

// Round 4
// 938.086 us; speedup vs baseline: 1.7896x; 1.7896x over previous
//
#include <hip/hip_runtime.h>
#include <math.h>

#define EPS 1e-3f
#define H 256
#define QDIM 6
#define DQDIM 4
#define NTRI 10
#define EPB 8    // elements per block
#define PADH 260 // padded row length (floats) to break bank conflicts

typedef _Float16 half8 __attribute__((ext_vector_type(8)));
typedef float floatx4 __attribute__((ext_vector_type(4)));

__device__ __forceinline__ float softplusf(float x) {
    if (x > 20.f) return x;
    return log1pf(expf(x));
}

// split 8 contiguous floats into fp16 hi + fp16 residual lo
__device__ __forceinline__ void split8(const float* __restrict__ p, half8& hi, half8& lo) {
    #pragma unroll
    for (int i = 0; i < 8; i++) {
        float a = p[i];
        _Float16 h = (_Float16)a;
        hi[i] = h;
        lo[i] = (_Float16)(a - (float)h);
    }
}

// split 8 strided floats (stride in floats)
__device__ __forceinline__ void split8s(const float* __restrict__ p, int stride, half8& hi, half8& lo) {
    #pragma unroll
    for (int i = 0; i < 8; i++) {
        float a = p[i * stride];
        _Float16 h = (_Float16)a;
        hi[i] = h;
        lo[i] = (_Float16)(a - (float)h);
    }
}

#define MFMA(A, B, C) __builtin_amdgcn_mfma_f32_16x16x32_f16((A), (B), (C), 0, 0, 0)

__global__ __launch_bounds__(256) void lnn_kernel(
    const float* __restrict__ x,
    const float* __restrict__ mW0, const float* __restrict__ mb0,
    const float* __restrict__ mW1, const float* __restrict__ mb1,
    const float* __restrict__ mW2, const float* __restrict__ mb2,
    const float* __restrict__ vW0, const float* __restrict__ vb0,
    const float* __restrict__ vW1, const float* __restrict__ vb1,
    const float* __restrict__ vW2, const float* __restrict__ vb2,
    float* __restrict__ out, int n)
{
    __shared__ float s_qd[EPB][12];
    __shared__ float s_h1[EPB][PADH];
    __shared__ float s_h2[EPB][PADH];
    __shared__ float s_eh2[EPB * 4][PADH];   // Eh2 seeds -> Eh1 -> gg1
    __shared__ float s_ent[EPB][NTRI];
    __shared__ float s_entbar[EPB][4][NTRI];
    __shared__ float s_L[EPB][4][4];
    __shared__ float s_J[EPB][4][6];
    __shared__ float s_dV[EPB][6];

    const int tid = threadIdx.x;
    const int e0 = blockIdx.x * EPB;
    const int lane = tid & 63;
    const int wid = tid >> 6;        // wave id 0..3
    const int fr = lane & 15;        // fragment row/col index
    const int fg = lane >> 4;        // k-group 0..3

    // ---- load q, dq ----
    if (tid < EPB * 10) {
        int e = tid / 10, c = tid % 10;
        int ge = e0 + e;
        s_qd[e][c] = (ge < n) ? x[ge * 10 + c] : 0.f;
    }
    __syncthreads();

    // ---- mass MLP layer 0: h1 = tanh(q @ W0 + b0) ----
    {
        const int j = tid;
        float w[QDIM];
        #pragma unroll
        for (int i = 0; i < QDIM; i++) w[i] = mW0[i * H + j];
        const float b = mb0[j];
        #pragma unroll
        for (int e = 0; e < EPB; e++) {
            float z = b;
            #pragma unroll
            for (int i = 0; i < QDIM; i++) z += s_qd[e][i] * w[i];
            s_h1[e][j] = tanhf(z);
        }
    }
    __syncthreads();

    // ---- mass layer 1 via MFMA (split fp16): z2 = h1 @ W1, h2 = tanh(z2+b1) ----
    {
        floatx4 acc[4];
        #pragma unroll
        for (int t = 0; t < 4; t++) acc[t] = (floatx4)(0.f);
        for (int kc = 0; kc < 8; kc++) {
            half8 ah, al;
            split8(&s_h1[fr & 7][kc * 32 + fg * 8], ah, al);
            #pragma unroll
            for (int t = 0; t < 4; t++) {
                const int j = (wid * 4 + t) * 16 + fr;
                half8 bh, bl;
                split8s(&mW1[(kc * 32 + fg * 8) * H + j], H, bh, bl);
                acc[t] = MFMA(ah, bh, acc[t]);
                acc[t] = MFMA(ah, bl, acc[t]);
                acc[t] = MFMA(al, bh, acc[t]);
            }
        }
        if (fg < 2) {
            #pragma unroll
            for (int t = 0; t < 4; t++) {
                const int j = (wid * 4 + t) * 16 + fr;
                const float b = mb1[j];
                #pragma unroll
                for (int rr = 0; rr < 4; rr++) {
                    const int e = fg * 4 + rr;
                    s_h2[e][j] = tanhf(acc[t][rr] + b);
                }
            }
        }
    }
    __syncthreads();

    // ---- ent = h2 @ W2 + b2 ----
    if (tid < EPB * NTRI) {
        int e = tid / NTRI, m = tid % NTRI;
        float acc = mb2[m];
        for (int j = 0; j < H; j++) acc += s_h2[e][j] * mW2[j * NTRI + m];
        s_ent[e][m] = acc;
    }
    __syncthreads();

    // ---- per-element: L, a = L^T dq, ent_bar seeds ----
    if (tid < EPB) {
        const int e = tid;
        const int ti[10] = {0,1,1,2,2,2,3,3,3,3};
        const int tj[10] = {0,0,1,0,1,2,0,1,2,3};
        float L[4][4];
        #pragma unroll
        for (int r = 0; r < 4; r++)
            #pragma unroll
            for (int c = 0; c < 4; c++) L[r][c] = 0.f;
        float sig[10];
        #pragma unroll
        for (int m = 0; m < 10; m++) {
            float v = s_ent[e][m];
            if (ti[m] == tj[m]) {
                sig[m] = 1.f / (1.f + expf(-v));
                L[ti[m]][tj[m]] = softplusf(v);
            } else {
                sig[m] = 1.f;
                L[ti[m]][tj[m]] = v;
            }
        }
        #pragma unroll
        for (int r = 0; r < 4; r++)
            #pragma unroll
            for (int c = 0; c < 4; c++) s_L[e][r][c] = L[r][c];
        float dq[4];
        #pragma unroll
        for (int r = 0; r < 4; r++) dq[r] = s_qd[e][6 + r];
        float a[4];
        #pragma unroll
        for (int c = 0; c < 4; c++) {
            float s = 0.f;
            #pragma unroll
            for (int r = 0; r < 4; r++) s += L[r][c] * dq[r];
            a[c] = s;
        }
        #pragma unroll
        for (int s = 0; s < 4; s++) {
            #pragma unroll
            for (int m = 0; m < 10; m++) {
                float v = ((ti[m] == s) ? a[tj[m]] : 0.f) + dq[ti[m]] * L[s][tj[m]];
                s_entbar[e][s][m] = v * sig[m];
            }
        }
    }
    __syncthreads();

    // ---- Eh2[e][s][j] = (1-h2^2) * (W2 @ ent_bar) ----
    {
        const int j = tid;
        float w2row[NTRI];
        #pragma unroll
        for (int m = 0; m < NTRI; m++) w2row[m] = mW2[j * NTRI + m];
        #pragma unroll
        for (int e = 0; e < EPB; e++) {
            const float h = s_h2[e][j];
            const float t2 = 1.f - h * h;
            #pragma unroll
            for (int s = 0; s < 4; s++) {
                float acc = 0.f;
                #pragma unroll
                for (int m = 0; m < NTRI; m++) acc += w2row[m] * s_entbar[e][s][m];
                s_eh2[e * 4 + s][j] = acc * t2;
            }
        }
    }
    __syncthreads();

    // ---- Eh1 via MFMA (split fp16): Eh1[es][k] = t1[e][k] * sum_j W1[k,j]*Eh2[es][j] ----
    {
        floatx4 acc[4][2];
        #pragma unroll
        for (int t = 0; t < 4; t++)
            #pragma unroll
            for (int mt = 0; mt < 2; mt++) acc[t][mt] = (floatx4)(0.f);
        for (int kc = 0; kc < 8; kc++) {
            half8 ah[2], al[2];
            #pragma unroll
            for (int mt = 0; mt < 2; mt++)
                split8(&s_eh2[mt * 16 + fr][kc * 32 + fg * 8], ah[mt], al[mt]);
            #pragma unroll
            for (int t = 0; t < 4; t++) {
                const int outk = (wid * 4 + t) * 16 + fr;
                half8 bh, bl;
                split8(&mW1[outk * H + kc * 32 + fg * 8], bh, bl);
                #pragma unroll
                for (int mt = 0; mt < 2; mt++) {
                    acc[t][mt] = MFMA(ah[mt], bh, acc[t][mt]);
                    acc[t][mt] = MFMA(ah[mt], bl, acc[t][mt]);
                    acc[t][mt] = MFMA(al[mt], bh, acc[t][mt]);
                }
            }
        }
        __syncthreads();   // all reads of s_eh2 (Eh2) done before overwrite with Eh1
        #pragma unroll
        for (int t = 0; t < 4; t++) {
            const int outk = (wid * 4 + t) * 16 + fr;
            #pragma unroll
            for (int mt = 0; mt < 2; mt++) {
                const int e = mt * 4 + fg;
                const float h = s_h1[e][outk];
                const float t1 = 1.f - h * h;
                #pragma unroll
                for (int rr = 0; rr < 4; rr++)
                    s_eh2[mt * 16 + fg * 4 + rr][outk] = acc[t][mt][rr] * t1;
            }
        }
    }
    __syncthreads();

    // ---- J[e][s][i] = sum_k W0[i,k] * Eh1[es][k] ----
    if (tid < EPB * 4 * 6) {
        const int i = tid % 6;
        const int es = tid / 6;
        float acc = 0.f;
        for (int k = 0; k < H; k++) acc += mW0[i * H + k] * s_eh2[es][k];
        s_J[es / 4][es % 4][i] = acc;
    }
    __syncthreads();

    // ---- V MLP layer 0: g1 -> s_h1 (overwrite) ----
    {
        const int j = tid;
        float w[QDIM];
        #pragma unroll
        for (int i = 0; i < QDIM; i++) w[i] = vW0[i * H + j];
        const float b = vb0[j];
        #pragma unroll
        for (int e = 0; e < EPB; e++) {
            float z = b;
            #pragma unroll
            for (int i = 0; i < QDIM; i++) z += s_qd[e][i] * w[i];
            s_h1[e][j] = tanhf(z);
        }
    }
    __syncthreads();

    // ---- V layer 1 via MFMA (split fp16) + seed: gg2 = (1-g2^2)*vW2[j] -> s_h2 ----
    {
        floatx4 acc[4];
        #pragma unroll
        for (int t = 0; t < 4; t++) acc[t] = (floatx4)(0.f);
        for (int kc = 0; kc < 8; kc++) {
            half8 ah, al;
            split8(&s_h1[fr & 7][kc * 32 + fg * 8], ah, al);
            #pragma unroll
            for (int t = 0; t < 4; t++) {
                const int j = (wid * 4 + t) * 16 + fr;
                half8 bh, bl;
                split8s(&vW1[(kc * 32 + fg * 8) * H + j], H, bh, bl);
                acc[t] = MFMA(ah, bh, acc[t]);
                acc[t] = MFMA(ah, bl, acc[t]);
                acc[t] = MFMA(al, bh, acc[t]);
            }
        }
        if (fg < 2) {
            #pragma unroll
            for (int t = 0; t < 4; t++) {
                const int j = (wid * 4 + t) * 16 + fr;
                const float b = vb1[j];
                const float w2 = vW2[j];
                #pragma unroll
                for (int rr = 0; rr < 4; rr++) {
                    const int e = fg * 4 + rr;
                    const float g2 = tanhf(acc[t][rr] + b);
                    s_h2[e][j] = (1.f - g2 * g2) * w2;
                }
            }
        }
    }
    __syncthreads();

    // ---- gg1 via MFMA (split fp16): gg1[e][k] = t1g * sum_j vW1[k,j]*gg2[e][j] ----
    {
        floatx4 acc[4];
        #pragma unroll
        for (int t = 0; t < 4; t++) acc[t] = (floatx4)(0.f);
        for (int kc = 0; kc < 8; kc++) {
            half8 ah, al;
            split8(&s_h2[fr & 7][kc * 32 + fg * 8], ah, al);
            #pragma unroll
            for (int t = 0; t < 4; t++) {
                const int outk = (wid * 4 + t) * 16 + fr;
                half8 bh, bl;
                split8(&vW1[outk * H + kc * 32 + fg * 8], bh, bl);
                acc[t] = MFMA(ah, bh, acc[t]);
                acc[t] = MFMA(ah, bl, acc[t]);
                acc[t] = MFMA(al, bh, acc[t]);
            }
        }
        __syncthreads();   // reads of s_eh2 by J phase long done; s_h2 reads done
        if (fg < 2) {
            #pragma unroll
            for (int t = 0; t < 4; t++) {
                const int outk = (wid * 4 + t) * 16 + fr;
                #pragma unroll
                for (int rr = 0; rr < 4; rr++) {
                    const int e = fg * 4 + rr;
                    const float g = s_h1[e][outk];
                    s_eh2[e][outk] = acc[t][rr] * (1.f - g * g);
                }
            }
        }
    }
    __syncthreads();

    // ---- dV[e][i] = sum_k vW0[i,k] * gg1[e][k] ----
    if (tid < EPB * 6) {
        const int e = tid / 6, i = tid % 6;
        float acc = 0.f;
        for (int k = 0; k < H; k++) acc += vW0[i * H + k] * s_eh2[e][k];
        s_dV[e][i] = acc;
    }
    __syncthreads();

    // ---- finalize per element ----
    if (tid < EPB && (e0 + tid) < n) {
        const int e = tid;
        float q[6], dq[4];
        #pragma unroll
        for (int i = 0; i < 6; i++) q[i] = s_qd[e][i];
        #pragma unroll
        for (int r = 0; r < 4; r++) dq[r] = s_qd[e][6 + r];
        const float x1a = q[2], x1b = q[3], x2a = q[4], x2b = q[5];
        float J[4][6];
        #pragma unroll
        for (int r = 0; r < 4; r++)
            #pragma unroll
            for (int i = 0; i < 6; i++) J[r][i] = s_J[e][r][i];

        float G[4][4];
        #pragma unroll
        for (int r = 0; r < 4; r++) {
            G[r][0] = J[r][0];
            G[r][1] = J[r][1];
            G[r][2] = -x2a * J[r][2] + x1a * J[r][4];
            G[r][3] = -x2b * J[r][3] + x1b * J[r][5];
        }
        float gL[6];
        #pragma unroll
        for (int i = 0; i < 6; i++) {
            float s = 0.f;
            #pragma unroll
            for (int r = 0; r < 4; r++) s += dq[r] * J[r][i];
            gL[i] = 0.5f * s - s_dV[e][i];
        }
        float dLdq[4];
        dLdq[0] = gL[0];
        dLdq[1] = gL[1];
        dLdq[2] = -x2a * gL[2] + x1a * gL[4];
        dLdq[3] = -x2b * gL[3] + x1b * gL[5];
        float b[4];
        #pragma unroll
        for (int r = 0; r < 4; r++) {
            float s = 0.f;
            #pragma unroll
            for (int c = 0; c < 4; c++) s += G[r][c] * dq[c];
            b[r] = dLdq[r] - s;
        }
        float L[4][4];
        #pragma unroll
        for (int r = 0; r < 4; r++)
            #pragma unroll
            for (int c = 0; c < 4; c++) L[r][c] = s_L[e][r][c];
        float M[4][4];
        #pragma unroll
        for (int r = 0; r < 4; r++)
            #pragma unroll
            for (int c = 0; c <= r; c++) {
                float s = 0.f;
                #pragma unroll
                for (int k = 0; k < 4; k++) s += L[r][k] * L[c][k];
                M[r][c] = s;
            }
        #pragma unroll
        for (int r = 0; r < 4; r++) M[r][r] += EPS;
        float C00 = sqrtf(M[0][0]);
        float C10 = M[1][0] / C00, C20 = M[2][0] / C00, C30 = M[3][0] / C00;
        float C11 = sqrtf(M[1][1] - C10 * C10);
        float C21 = (M[2][1] - C20 * C10) / C11;
        float C31 = (M[3][1] - C30 * C10) / C11;
        float C22 = sqrtf(M[2][2] - C20 * C20 - C21 * C21);
        float C32 = (M[3][2] - C30 * C20 - C31 * C21) / C22;
        float C33 = sqrtf(M[3][3] - C30 * C30 - C31 * C31 - C32 * C32);
        float y0 = b[0] / C00;
        float y1 = (b[1] - C10 * y0) / C11;
        float y2 = (b[2] - C20 * y0 - C21 * y1) / C22;
        float y3 = (b[3] - C30 * y0 - C31 * y1 - C32 * y2) / C33;
        float d3 = y3 / C33;
        float d2 = (y2 - C32 * d3) / C22;
        float d1 = (y1 - C21 * d2 - C31 * d3) / C11;
        float d0 = (y0 - C10 * d1 - C20 * d2 - C30 * d3) / C00;

        float* o = &out[(e0 + e) * 10];
        o[0] = dq[0];
        o[1] = dq[1];
        o[2] = -x2a * dq[2];
        o[3] = -x2b * dq[3];
        o[4] = x1a * dq[2];
        o[5] = x1b * dq[3];
        o[6] = d0; o[7] = d1; o[8] = d2; o[9] = d3;
    }
}

extern "C" void kernel_launch(void* const* d_in, const int* in_sizes, int n_in,
                              void* d_out, int out_size, void* d_ws, size_t ws_size,
                              hipStream_t stream) {
    const float* x   = (const float*)d_in[0];
    const float* mW0 = (const float*)d_in[1];
    const float* mb0 = (const float*)d_in[2];
    const float* mW1 = (const float*)d_in[3];
    const float* mb1 = (const float*)d_in[4];
    const float* mW2 = (const float*)d_in[5];
    const float* mb2 = (const float*)d_in[6];
    const float* vW0 = (const float*)d_in[7];
    const float* vb0 = (const float*)d_in[8];
    const float* vW1 = (const float*)d_in[9];
    const float* vb1 = (const float*)d_in[10];
    const float* vW2 = (const float*)d_in[11];
    const float* vb2 = (const float*)d_in[12];
    float* out = (float*)d_out;
    const int n = in_sizes[0] / 10;
    const int blocks = (n + EPB - 1) / EPB;
    lnn_kernel<<<blocks, 256, 0, stream>>>(x, mW0, mb0, mW1, mb1, mW2, mb2,
                                           vW0, vb0, vW1, vb1, vW2, vb2, out, n);
}